// Round 11
// baseline (1766.092 us; speedup 1.0000x reference)
//
#include <hip/hip_runtime.h>
#include <stdint.h>

#define B_ 4
#define H_ 16
#define S_ 2048
#define D_ 64
#define QBLK 16
#define NTH 1024
#define NWAVES 16
#define KSLAB 128                     /* per-wave k coverage */
#define NWIN 4                        /* 32-k windows per slab */
#define ETS 136                       /* etile row stride in shorts (128 + 8 pad) */

typedef __attribute__((ext_vector_type(8))) short short8;
typedef __attribute__((ext_vector_type(4))) float float4v;
typedef __attribute__((ext_vector_type(4))) unsigned int uint4v;
typedef __attribute__((ext_vector_type(2))) unsigned int uint2v;

static __device__ __forceinline__ short f2bf(float f) {
  uint32_t u = __builtin_bit_cast(uint32_t, f);
  u = (u + 0x7FFFu + ((u >> 16) & 1u)) >> 16;   // RNE
  return (short)u;
}
static __device__ __forceinline__ float bf2f(short s) {
  uint32_t u = ((uint32_t)(uint16_t)s) << 16;
  return __builtin_bit_cast(float, u);
}
// packed f32x2 -> bf16x2 (RNE)
static __device__ __forceinline__ uint32_t cvtpk(float lo, float hi) {
  uint32_t r;
  asm("v_cvt_pk_bf16_f32 %0, %1, %2" : "=v"(r) : "v"(lo), "v"(hi));
  return r;
}
static __device__ __forceinline__ uint32_t nz4(uint32_t d) {
  uint32_t x = (d & 0x7F7F7F7Fu) + 0x7F7F7F7Fu;
  x = (x | d) & 0x80808080u;
  return x >> 7;
}
static __device__ __forceinline__ uint32_t nib(uint32_t d) {
  return ((nz4(d) * 0x01020408u) >> 24) & 0xFu;
}

// dynamic LDS layout (bytes)
#define ETILE_BYTES (NWAVES * 16 * ETS * 2)        // 69632
#define MBITS_OFF   ETILE_BYTES
#define CBUF_OFF    (MBITS_OFF + QBLK * 65 * 4)    // +4160
#define LSUM_OFF    (CBUF_OFF + QBLK * 65 * 4)     // +4160
#define LINV_OFF    (LSUM_OFF + 64)
#define SMEM_BYTES  (LINV_OFF + 64)                // 78080 -> 2 blocks/CU, 32 waves

#define KBF_OFF    ((size_t)64)
#define KBF_BYTES  ((size_t)B_ * H_ * S_ * D_ * 2)
#define VT_OFF     (KBF_OFF + KBF_BYTES)
#define VT_BYTES   ((size_t)B_ * H_ * S_ * D_ * 2)

__global__ void detect_mask_dtype(const uint8_t* __restrict__ m, uint32_t* flag) {
  uint32_t a = 0, b = 0;
  for (int i = threadIdx.x; i < 65536; i += 256) {
    uint8_t x = m[i];
    if (i & 3) a |= x; else b |= x;
  }
  uint32_t bits = (a ? 1u : 0u) | (b ? 2u : 0u);
  if (bits) atomicOr(flag, bits);
}

__global__ __launch_bounds__(256) void prep_k(const float* __restrict__ K,
                                              short* __restrict__ Kbf) {
  size_t base = ((size_t)blockIdx.x * 256 + threadIdx.x) * 8;
  float4v a = __builtin_nontemporal_load((const float4v*)(K + base));
  float4v b = __builtin_nontemporal_load((const float4v*)(K + base + 4));
  short8 o;
  o[0]=f2bf(a.x); o[1]=f2bf(a.y); o[2]=f2bf(a.z); o[3]=f2bf(a.w);
  o[4]=f2bf(b.x); o[5]=f2bf(b.y); o[6]=f2bf(b.z); o[7]=f2bf(b.w);
  *(short8*)(Kbf + base) = o;
}

__global__ __launch_bounds__(256) void prep_vt(const float* __restrict__ V,
                                               short* __restrict__ VT) {
  __shared__ short tile[64][72];
  int bh = blockIdx.x >> 5, k0 = (blockIdx.x & 31) * 64;
  const float* src = V + ((size_t)bh * S_ + k0) * D_;
  int t = threadIdx.x;
  int r = t >> 2, c0 = (t & 3) * 16;
#pragma unroll
  for (int j = 0; j < 4; ++j) {
    float4v f = __builtin_nontemporal_load((const float4v*)(src + (size_t)r * D_ + c0 + j * 4));
    tile[r][c0 + j*4 + 0] = f2bf(f.x);
    tile[r][c0 + j*4 + 1] = f2bf(f.y);
    tile[r][c0 + j*4 + 2] = f2bf(f.z);
    tile[r][c0 + j*4 + 3] = f2bf(f.w);
  }
  __syncthreads();
  int d = t >> 2, ks0 = (t & 3) * 16;
  short* dst = VT + (size_t)bh * D_ * S_ + (size_t)d * S_ + k0 + ks0;
#pragma unroll
  for (int half = 0; half < 2; ++half) {
    short8 o;
#pragma unroll
    for (int i = 0; i < 8; ++i) o[i] = tile[ks0 + half * 8 + i][d];
    *(short8*)(dst + half * 8) = o;
  }
}

template <int PREP>
__global__ __launch_bounds__(NTH, 8) void attn_fused(
    const float* __restrict__ Q, const float* __restrict__ K,
    const float* __restrict__ V, const float* __restrict__ scale_p,
    const uint8_t* __restrict__ M, const uint32_t* __restrict__ flag,
    const short* __restrict__ Kbf, const short* __restrict__ VT,
    float* __restrict__ outC, float* __restrict__ outA)
{
  extern __shared__ char smem[];
  short*    etileA = (short*)smem;                      // [NWAVES][16][ETS]
  uint32_t* mbits  = (uint32_t*)(smem + MBITS_OFF);     // [QBLK][65]
  float*    cbuf   = (float*)(smem + CBUF_OFF);         // [QBLK][65]
  float*    lsum   = (float*)(smem + LSUM_OFF);
  float*    linv   = (float*)(smem + LINV_OFF);

  // bh-exclusive XCD swizzle: 8192 blocks, XCD x gets bx in [x*1024, x*1024+1024)
  const int bx  = (blockIdx.x & 7) * 1024 + (blockIdx.x >> 3);
  const int bh  = bx >> 7;
  const int q0  = (bx & 127) * QBLK;

  const int tid  = threadIdx.x;
  const int w    = tid >> 6;
  const int lane = tid & 63;
  const int g    = lane >> 4;
  const int c    = lane & 15;
  const int kslab0 = w * KSLAB;

  const float scale = scale_p[0];
  const uint32_t fl = flag[0];

  const float* Qp  = Q + (size_t)bh * S_ * D_;
  const short* Kbp = Kbf + (size_t)bh * S_ * D_;
  const short* VTp = VT + (size_t)bh * D_ * S_;
  const float* Kfp = K + (size_t)bh * S_ * D_;
  const float* Vfp = V + (size_t)bh * S_ * D_;
  short* etile = etileA + w * 16 * ETS;

  short8 kf[2][4];
#define LOADK(BUF, WIN) do {                                                   \
    const short* kr0_ = Kbp + (size_t)(kslab0 + (WIN) * 32 + c) * D_ + g * 8;  \
    kf[BUF][0] = *(const short8*)kr0_;                                         \
    kf[BUF][1] = *(const short8*)(kr0_ + 32);                                  \
    const short* kr1_ = kr0_ + 16 * D_;                                        \
    kf[BUF][2] = *(const short8*)kr1_;                                         \
    kf[BUF][3] = *(const short8*)(kr1_ + 32);                                  \
  } while (0)

  float4v qa = *(const float4v*)(Qp + (size_t)(q0 + c) * D_ + g * 8);
  float4v qb = *(const float4v*)(Qp + (size_t)(q0 + c) * D_ + g * 8 + 4);
  float4v qc2 = *(const float4v*)(Qp + (size_t)(q0 + c) * D_ + 32 + g * 8);
  float4v qd = *(const float4v*)(Qp + (size_t)(q0 + c) * D_ + 32 + g * 8 + 4);
  if (PREP) LOADK(0, 0);

  // ---- mask bitmap prologue: [16][2048] bits ----
  {
    const int row = tid >> 6;                  // 0..15
    const int wq  = tid & 63;                  // 1 word (32 bits) per thread
    if (fl == 3u) {                            // byte mask
      const uint8_t* mrow = M + ((size_t)(bh * S_ + q0 + row)) * S_ + wq * 32;
      uint4v a = __builtin_nontemporal_load((const uint4v*)mrow);
      uint4v b = __builtin_nontemporal_load((const uint4v*)(mrow + 16));
      mbits[row * 65 + wq] =
          nib(a.x) | (nib(a.y) << 4) | (nib(a.z) << 8)  | (nib(a.w) << 12)
        | (nib(b.x) << 16) | (nib(b.y) << 20) | (nib(b.z) << 24) | (nib(b.w) << 28);
    } else {                                   // 4-byte mask
      const uint32_t* mrow = (const uint32_t*)M + ((size_t)(bh * S_ + q0 + row)) * S_ + wq * 32;
      uint32_t bits = 0;
#pragma unroll
      for (int u = 0; u < 8; ++u) {
        uint4v wv = __builtin_nontemporal_load((const uint4v*)(mrow + u * 4));
        uint32_t nzb = (wv.x ? 1u : 0u) | (wv.y ? 2u : 0u) | (wv.z ? 4u : 0u) | (wv.w ? 8u : 0u);
        bits |= nzb << (u * 4);
      }
      mbits[row * 65 + wq] = bits;
    }
    for (int i = tid; i < QBLK * 65; i += NTH) cbuf[i] = 0.0f;
    if (tid < QBLK) lsum[tid] = 0.0f;
  }
  __syncthreads();

  // ---- Q as B-frag: lane holds Q[q0+c][.] ----
  short8 qB[2];
  {
    short8 f;
    f[0]=f2bf(qa.x); f[1]=f2bf(qa.y); f[2]=f2bf(qa.z); f[3]=f2bf(qa.w);
    f[4]=f2bf(qb.x); f[5]=f2bf(qb.y); f[6]=f2bf(qb.z); f[7]=f2bf(qb.w);
    qB[0] = f;
    f[0]=f2bf(qc2.x); f[1]=f2bf(qc2.y); f[2]=f2bf(qc2.z); f[3]=f2bf(qc2.w);
    f[4]=f2bf(qd.x); f[5]=f2bf(qd.y); f[6]=f2bf(qd.z); f[7]=f2bf(qd.w);
    qB[1] = f;
  }

  const uint32_t* mrowp = &mbits[c * 65 + (kslab0 >> 5)];
  float rsv = 0.0f;
  float4v cacc[4];
#pragma unroll
  for (int nd = 0; nd < 4; ++nd) cacc[nd] = (float4v){0.f, 0.f, 0.f, 0.f};

  if (PREP) {
#pragma unroll
    for (int win = 0; win < NWIN; ++win) {
      const int cur = win & 1;
      const int kwin = kslab0 + win * 32;

      // V frags for current window, issued early
      short8 vA[4];
#pragma unroll
      for (int nd = 0; nd < 4; ++nd)
        vA[nd] = *(const short8*)&VTp[(size_t)(nd * 16 + c) * S_ + kwin + g * 8];

      short8 a0 = kf[cur][0], a1 = kf[cur][1], a2 = kf[cur][2], a3 = kf[cur][3];
      if (win + 1 < NWIN) { if (cur == 0) LOADK(1, win + 1); else LOADK(0, win + 1); }

      float4v acc0 = (float4v){0.f,0.f,0.f,0.f};
      float4v acc1 = (float4v){0.f,0.f,0.f,0.f};
      acc0 = __builtin_amdgcn_mfma_f32_16x16x32_bf16(a0, qB[0], acc0, 0, 0, 0);
      acc0 = __builtin_amdgcn_mfma_f32_16x16x32_bf16(a1, qB[1], acc0, 0, 0, 0);
      acc1 = __builtin_amdgcn_mfma_f32_16x16x32_bf16(a2, qB[0], acc1, 0, 0, 0);
      acc1 = __builtin_amdgcn_mfma_f32_16x16x32_bf16(a3, qB[1], acc1, 0, 0, 0);

      const uint32_t mw = mrowp[win];
      float e0[4], e1[4];
#pragma unroll
      for (int r = 0; r < 4; ++r) {
        e0[r] = ((mw >> (4 * g + r)) & 1u)      ? 1.0f : __expf(acc0[r] * scale);
        e1[r] = ((mw >> (16 + 4 * g + r)) & 1u) ? 1.0f : __expf(acc1[r] * scale);
        rsv += e0[r] + e1[r];
      }
      uint2v lo, hi2;
      lo.x  = cvtpk(e0[0], e0[1]);  lo.y  = cvtpk(e0[2], e0[3]);
      hi2.x = cvtpk(e1[0], e1[1]);  hi2.y = cvtpk(e1[2], e1[3]);
      *(uint2v*)&etile[c * ETS + win * 32 + 4 * g]      = lo;
      *(uint2v*)&etile[c * ETS + win * 32 + 16 + 4 * g] = hi2;

      const short8 bfrag = *(const short8*)&etile[c * ETS + win * 32 + g * 8];
      cacc[0] = __builtin_amdgcn_mfma_f32_16x16x32_bf16(vA[0], bfrag, cacc[0], 0, 0, 0);
      cacc[1] = __builtin_amdgcn_mfma_f32_16x16x32_bf16(vA[1], bfrag, cacc[1], 0, 0, 0);
      cacc[2] = __builtin_amdgcn_mfma_f32_16x16x32_bf16(vA[2], bfrag, cacc[2], 0, 0, 0);
      cacc[3] = __builtin_amdgcn_mfma_f32_16x16x32_bf16(vA[3], bfrag, cacc[3], 0, 0, 0);
    }
  } else {
#pragma unroll
    for (int win = 0; win < NWIN; ++win) {
      const int kwin = kslab0 + win * 32;
      short8 a0, a1, a2, a3, vA[4];
      const float* kr = Kfp + (size_t)(kwin + c) * D_ + g * 8;
      const float* kr1 = kr + 16 * D_;
#pragma unroll
      for (int e = 0; e < 8; ++e) {
        a0[e] = f2bf(kr[e]);  a1[e] = f2bf(kr[32 + e]);
        a2[e] = f2bf(kr1[e]); a3[e] = f2bf(kr1[32 + e]);
      }
#pragma unroll
      for (int nd = 0; nd < 4; ++nd) {
        const float* vc = Vfp + (size_t)(kwin + g * 8) * D_ + nd * 16 + c;
#pragma unroll
        for (int e = 0; e < 8; ++e) vA[nd][e] = f2bf(vc[(size_t)e * D_]);
      }
      float4v acc0 = (float4v){0.f,0.f,0.f,0.f};
      float4v acc1 = (float4v){0.f,0.f,0.f,0.f};
      acc0 = __builtin_amdgcn_mfma_f32_16x16x32_bf16(a0, qB[0], acc0, 0, 0, 0);
      acc0 = __builtin_amdgcn_mfma_f32_16x16x32_bf16(a1, qB[1], acc0, 0, 0, 0);
      acc1 = __builtin_amdgcn_mfma_f32_16x16x32_bf16(a2, qB[0], acc1, 0, 0, 0);
      acc1 = __builtin_amdgcn_mfma_f32_16x16x32_bf16(a3, qB[1], acc1, 0, 0, 0);
      const uint32_t mw = mrowp[win];
      float e0[4], e1[4];
#pragma unroll
      for (int r = 0; r < 4; ++r) {
        e0[r] = ((mw >> (4 * g + r)) & 1u)      ? 1.0f : __expf(acc0[r] * scale);
        e1[r] = ((mw >> (16 + 4 * g + r)) & 1u) ? 1.0f : __expf(acc1[r] * scale);
        rsv += e0[r] + e1[r];
      }
      uint2v lo, hi2;
      lo.x  = cvtpk(e0[0], e0[1]);  lo.y  = cvtpk(e0[2], e0[3]);
      hi2.x = cvtpk(e1[0], e1[1]);  hi2.y = cvtpk(e1[2], e1[3]);
      *(uint2v*)&etile[c * ETS + win * 32 + 4 * g]      = lo;
      *(uint2v*)&etile[c * ETS + win * 32 + 16 + 4 * g] = hi2;
      const short8 bfrag = *(const short8*)&etile[c * ETS + win * 32 + g * 8];
#pragma unroll
      for (int nd = 0; nd < 4; ++nd)
        cacc[nd] = __builtin_amdgcn_mfma_f32_16x16x32_bf16(vA[nd], bfrag, cacc[nd], 0, 0, 0);
    }
  }
#undef LOADK

  // ---- reductions ----
  rsv += __shfl_xor(rsv, 16);
  rsv += __shfl_xor(rsv, 32);
  if (lane < 16) atomicAdd(&lsum[lane], rsv);
#pragma unroll
  for (int nd = 0; nd < 4; ++nd)
#pragma unroll
    for (int r = 0; r < 4; ++r)
      atomicAdd(&cbuf[c * 65 + nd * 16 + 4 * g + r], cacc[nd][r]);
  __syncthreads();

  if (tid < QBLK) linv[tid] = 1.0f / lsum[tid];
  __syncthreads();

  // ---- context write ----
  if (tid < QBLK * D_ / 4) {
    const int row = tid >> 4, d0 = (tid & 15) * 4;
    const float inv = linv[row];
    float4v cv;
    cv.x = cbuf[row * 65 + d0 + 0] * inv;
    cv.y = cbuf[row * 65 + d0 + 1] * inv;
    cv.z = cbuf[row * 65 + d0 + 2] * inv;
    cv.w = cbuf[row * 65 + d0 + 3] * inv;
    *(float4v*)&outC[((size_t)(bh * S_ + q0 + row)) * D_ + d0] = cv;
  }

  // ---- phase 2: full-line normalized attention stores (2 rows / instr) ----
  {
    const int rsel = lane >> 5;                 // 0..1
    const int colq = (lane & 31) * 4;           // 0..124
    float* abase = outA + ((size_t)(bh * S_ + q0)) * S_ + kslab0 + colq;
#pragma unroll
    for (int p = 0; p < 8; ++p) {
      const int r16 = p * 2 + rsel;
      const float inv = linv[r16];
      const uint2v ev = *(const uint2v*)&etile[r16 * ETS + colq];
      float4v av;
      av.x = bf2f((short)(ev.x & 0xffff)) * inv;
      av.y = bf2f((short)(ev.x >> 16))    * inv;
      av.z = bf2f((short)(ev.y & 0xffff)) * inv;
      av.w = bf2f((short)(ev.y >> 16))    * inv;
      __builtin_nontemporal_store(av, (float4v*)(abase + (size_t)r16 * S_));
    }
  }
}

extern "C" void kernel_launch(void* const* d_in, const int* in_sizes, int n_in,
                              void* d_out, int out_size, void* d_ws, size_t ws_size,
                              hipStream_t stream) {
  const float*   Q     = (const float*)d_in[0];
  const float*   K     = (const float*)d_in[1];
  const float*   V     = (const float*)d_in[2];
  const float*   scale = (const float*)d_in[3];
  const uint8_t* M     = (const uint8_t*)d_in[4];
  uint32_t* flag = (uint32_t*)d_ws;
  short* Kbf = (short*)((char*)d_ws + KBF_OFF);
  short* VT  = (short*)((char*)d_ws + VT_OFF);
  float* outC = (float*)d_out;
  float* outA = outC + (size_t)B_ * H_ * S_ * D_;

  hipMemsetAsync(flag, 0, 4, stream);
  detect_mask_dtype<<<dim3(1), dim3(256), 0, stream>>>(M, flag);

  const bool prep = ws_size >= VT_OFF + VT_BYTES;
  const int grid = B_ * H_ * (S_ / QBLK);       // 8192
  if (prep) {
    prep_k<<<dim3((B_ * H_ * S_ * D_) / (256 * 8)), dim3(256), 0, stream>>>(K, Kbf);
    prep_vt<<<dim3(B_ * H_ * (S_ / 64)), dim3(256), 0, stream>>>(V, VT);
    hipFuncSetAttribute(reinterpret_cast<const void*>(attn_fused<1>),
                        hipFuncAttributeMaxDynamicSharedMemorySize, SMEM_BYTES);
    attn_fused<1><<<dim3(grid), dim3(NTH), SMEM_BYTES, stream>>>(
        Q, K, V, scale, M, flag, Kbf, VT, outC, outA);
  } else {
    hipFuncSetAttribute(reinterpret_cast<const void*>(attn_fused<0>),
                        hipFuncAttributeMaxDynamicSharedMemorySize, SMEM_BYTES);
    attn_fused<0><<<dim3(grid), dim3(NTH), SMEM_BYTES, stream>>>(
        Q, K, V, scale, M, flag, Kbf, VT, outC, outA);
  }
}

// Round 12
// 1391.758 us; speedup vs baseline: 1.2690x; 1.2690x over previous
//
#include <hip/hip_runtime.h>
#include <stdint.h>

#define B_ 4
#define H_ 16
#define S_ 2048
#define D_ 64
#define QBLK 16
#define NTH 1024
#define NPAIR 8                       /* wave-pairs; pair owns 256-k slab */
#define KSLAB 256
#define NWIN 8                        /* 32-k windows per slab */
#define ETS 264                       /* per-pair etile row stride (shorts) */

typedef __attribute__((ext_vector_type(8))) short short8;
typedef __attribute__((ext_vector_type(4))) float float4v;
typedef __attribute__((ext_vector_type(4))) unsigned int uint4v;
typedef __attribute__((ext_vector_type(2))) unsigned int uint2v;

static __device__ __forceinline__ short f2bf(float f) {
  uint32_t u = __builtin_bit_cast(uint32_t, f);
  u = (u + 0x7FFFu + ((u >> 16) & 1u)) >> 16;   // RNE
  return (short)u;
}
static __device__ __forceinline__ float bf2f(short s) {
  uint32_t u = ((uint32_t)(uint16_t)s) << 16;
  return __builtin_bit_cast(float, u);
}
static __device__ __forceinline__ uint32_t cvtpk(float lo, float hi) {
  uint32_t r;
  asm("v_cvt_pk_bf16_f32 %0, %1, %2" : "=v"(r) : "v"(lo), "v"(hi));
  return r;
}
static __device__ __forceinline__ uint32_t nz4(uint32_t d) {
  uint32_t x = (d & 0x7F7F7F7Fu) + 0x7F7F7F7Fu;
  x = (x | d) & 0x80808080u;
  return x >> 7;
}
static __device__ __forceinline__ uint32_t nib(uint32_t d) {
  return ((nz4(d) * 0x01020408u) >> 24) & 0xFu;
}

// dynamic LDS layout (bytes)
#define ETILE_BYTES (NPAIR * 16 * ETS * 2)         // 67584
#define MBITS_OFF   ETILE_BYTES
#define CBUF_OFF    (MBITS_OFF + QBLK * 65 * 4)
#define LSUM_OFF    (CBUF_OFF + QBLK * 65 * 4)
#define LINV_OFF    (LSUM_OFF + 64)
#define SMEM_BYTES  (LINV_OFF + 64)                // 76032 -> 2 blocks/CU, 32 waves

#define KBF_OFF    ((size_t)64)
#define KBF_BYTES  ((size_t)B_ * H_ * S_ * D_ * 2)
#define VT_OFF     (KBF_OFF + KBF_BYTES)
#define VT_BYTES   ((size_t)B_ * H_ * S_ * D_ * 2)

__global__ void detect_mask_dtype(const uint8_t* __restrict__ m, uint32_t* flag) {
  uint32_t a = 0, b = 0;
  for (int i = threadIdx.x; i < 65536; i += 256) {
    uint8_t x = m[i];
    if (i & 3) a |= x; else b |= x;
  }
  uint32_t bits = (a ? 1u : 0u) | (b ? 2u : 0u);
  if (bits) atomicOr(flag, bits);
}

__global__ __launch_bounds__(256) void prep_k(const float* __restrict__ K,
                                              short* __restrict__ Kbf) {
  size_t base = ((size_t)blockIdx.x * 256 + threadIdx.x) * 8;
  float4v a = __builtin_nontemporal_load((const float4v*)(K + base));
  float4v b = __builtin_nontemporal_load((const float4v*)(K + base + 4));
  short8 o;
  o[0]=f2bf(a.x); o[1]=f2bf(a.y); o[2]=f2bf(a.z); o[3]=f2bf(a.w);
  o[4]=f2bf(b.x); o[5]=f2bf(b.y); o[6]=f2bf(b.z); o[7]=f2bf(b.w);
  *(short8*)(Kbf + base) = o;
}

__global__ __launch_bounds__(256) void prep_vt(const float* __restrict__ V,
                                               short* __restrict__ VT) {
  __shared__ short tile[64][72];
  int bh = blockIdx.x >> 5, k0 = (blockIdx.x & 31) * 64;
  const float* src = V + ((size_t)bh * S_ + k0) * D_;
  int t = threadIdx.x;
  int r = t >> 2, c0 = (t & 3) * 16;
#pragma unroll
  for (int j = 0; j < 4; ++j) {
    float4v f = __builtin_nontemporal_load((const float4v*)(src + (size_t)r * D_ + c0 + j * 4));
    tile[r][c0 + j*4 + 0] = f2bf(f.x);
    tile[r][c0 + j*4 + 1] = f2bf(f.y);
    tile[r][c0 + j*4 + 2] = f2bf(f.z);
    tile[r][c0 + j*4 + 3] = f2bf(f.w);
  }
  __syncthreads();
  int d = t >> 2, ks0 = (t & 3) * 16;
  short* dst = VT + (size_t)bh * D_ * S_ + (size_t)d * S_ + k0 + ks0;
#pragma unroll
  for (int half = 0; half < 2; ++half) {
    short8 o;
#pragma unroll
    for (int i = 0; i < 8; ++i) o[i] = tile[ks0 + half * 8 + i][d];
    *(short8*)(dst + half * 8) = o;
  }
}

template <int PREP>
__global__ __launch_bounds__(NTH, 8) void attn_fused(
    const float* __restrict__ Q, const float* __restrict__ K,
    const float* __restrict__ V, const float* __restrict__ scale_p,
    const uint8_t* __restrict__ M, const uint32_t* __restrict__ flag,
    const short* __restrict__ Kbf, const short* __restrict__ VT,
    float* __restrict__ outC, float* __restrict__ outA)
{
  extern __shared__ char smem[];
  short*    etileA = (short*)smem;                      // [NPAIR][16][ETS]
  uint32_t* mbits  = (uint32_t*)(smem + MBITS_OFF);     // [QBLK][65]
  float*    cbuf   = (float*)(smem + CBUF_OFF);         // [QBLK][65]
  float*    lsum   = (float*)(smem + LSUM_OFF);
  float*    linv   = (float*)(smem + LINV_OFF);

  // XCD-chunked bijective swizzle: 8192 blocks, 1024 per XCD
  const int bx  = (blockIdx.x & 7) * 1024 + (blockIdx.x >> 3);
  const int bh  = bx >> 7;
  const int q0  = (bx & 127) * QBLK;

  const int tid  = threadIdx.x;
  const int w    = tid >> 6;
  const int lane = tid & 63;
  const int g    = lane >> 4;
  const int c    = lane & 15;
  const int pair  = w >> 1;                    // 0..7
  const int dhalf = w & 1;                     // 0..1 : d columns dhalf*32..+31
  const int kslab0 = pair * KSLAB;

  const float scale = scale_p[0];
  const uint32_t fl = flag[0];

  const float* Qp  = Q + (size_t)bh * S_ * D_;
  const short* Kbp = Kbf + (size_t)bh * S_ * D_;
  const short* VTp = VT + (size_t)bh * D_ * S_;
  const float* Kfp = K + (size_t)bh * S_ * D_;
  const float* Vfp = V + (size_t)bh * S_ * D_;
  short* etile = etileA + pair * 16 * ETS;

  // ---- mask bitmap prologue: [16][2048] bits, 1 word/thread ----
  {
    const int row = tid >> 6;                  // 0..15
    const int wq  = tid & 63;
    if (fl == 3u) {                            // byte mask
      const uint8_t* mrow = M + ((size_t)(bh * S_ + q0 + row)) * S_ + wq * 32;
      uint4v a = __builtin_nontemporal_load((const uint4v*)mrow);
      uint4v b = __builtin_nontemporal_load((const uint4v*)(mrow + 16));
      mbits[row * 65 + wq] =
          nib(a.x) | (nib(a.y) << 4) | (nib(a.z) << 8)  | (nib(a.w) << 12)
        | (nib(b.x) << 16) | (nib(b.y) << 20) | (nib(b.z) << 24) | (nib(b.w) << 28);
    } else {                                   // 4-byte mask
      const uint32_t* mrow = (const uint32_t*)M + ((size_t)(bh * S_ + q0 + row)) * S_ + wq * 32;
      uint32_t bits = 0;
#pragma unroll
      for (int u = 0; u < 8; ++u) {
        uint4v wv = __builtin_nontemporal_load((const uint4v*)(mrow + u * 4));
        uint32_t nzb = (wv.x ? 1u : 0u) | (wv.y ? 2u : 0u) | (wv.z ? 4u : 0u) | (wv.w ? 8u : 0u);
        bits |= nzb << (u * 4);
      }
      mbits[row * 65 + wq] = bits;
    }
    for (int i = tid; i < QBLK * 65; i += NTH) cbuf[i] = 0.0f;
    if (tid < QBLK) lsum[tid] = 0.0f;
  }
  __syncthreads();

  // ---- Q as B-frag: lane holds Q[q0+c][.] ----
  short8 qB[2];
  {
    const float* qr = Qp + (size_t)(q0 + c) * D_;
    float4v x0 = *(const float4v*)(qr + g * 8);
    float4v x1 = *(const float4v*)(qr + g * 8 + 4);
    float4v y0 = *(const float4v*)(qr + 32 + g * 8);
    float4v y1 = *(const float4v*)(qr + 32 + g * 8 + 4);
    short8 f;
    f[0]=f2bf(x0.x); f[1]=f2bf(x0.y); f[2]=f2bf(x0.z); f[3]=f2bf(x0.w);
    f[4]=f2bf(x1.x); f[5]=f2bf(x1.y); f[6]=f2bf(x1.z); f[7]=f2bf(x1.w);
    qB[0] = f;
    f[0]=f2bf(y0.x); f[1]=f2bf(y0.y); f[2]=f2bf(y0.z); f[3]=f2bf(y0.w);
    f[4]=f2bf(y1.x); f[5]=f2bf(y1.y); f[6]=f2bf(y1.z); f[7]=f2bf(y1.w);
    qB[1] = f;
  }

  const uint32_t* mrowp = &mbits[c * 65 + (kslab0 >> 5)];
  const int srcA = ((2 * g) & 3) * 16 + c;     // shuffle-transpose sources (R5)
  const int srcB = srcA + 16;
  const bool hi = g >= 2;

  float rsv = 0.0f;
  float4v cacc[2];
  cacc[0] = (float4v){0.f, 0.f, 0.f, 0.f};
  cacc[1] = (float4v){0.f, 0.f, 0.f, 0.f};

  // ---- phase 1: QK (duplicated in pair) -> exp -> E reg/LDS -> shuffle -> half-PV ----
#pragma unroll 2
  for (int win = 0; win < NWIN; ++win) {
    const int kwin = kslab0 + win * 32;

    // K frags (transient; die before vA lives)
    float4v acc0 = (float4v){0.f,0.f,0.f,0.f};
    float4v acc1 = (float4v){0.f,0.f,0.f,0.f};
    if (PREP) {
      const short* kr = Kbp + (size_t)(kwin + c) * D_ + g * 8;
      const short* kr1 = kr + 16 * D_;
      short8 a0 = *(const short8*)kr,  a1 = *(const short8*)(kr + 32);
      short8 a2 = *(const short8*)kr1, a3 = *(const short8*)(kr1 + 32);
      acc0 = __builtin_amdgcn_mfma_f32_16x16x32_bf16(a0, qB[0], acc0, 0, 0, 0);
      acc0 = __builtin_amdgcn_mfma_f32_16x16x32_bf16(a1, qB[1], acc0, 0, 0, 0);
      acc1 = __builtin_amdgcn_mfma_f32_16x16x32_bf16(a2, qB[0], acc1, 0, 0, 0);
      acc1 = __builtin_amdgcn_mfma_f32_16x16x32_bf16(a3, qB[1], acc1, 0, 0, 0);
    } else {
      const float* kr = Kfp + (size_t)(kwin + c) * D_ + g * 8;
      const float* kr1 = kr + 16 * D_;
      short8 a0, a1, a2, a3;
#pragma unroll
      for (int e = 0; e < 8; ++e) {
        a0[e] = f2bf(kr[e]);  a1[e] = f2bf(kr[32 + e]);
        a2[e] = f2bf(kr1[e]); a3[e] = f2bf(kr1[32 + e]);
      }
      acc0 = __builtin_amdgcn_mfma_f32_16x16x32_bf16(a0, qB[0], acc0, 0, 0, 0);
      acc0 = __builtin_amdgcn_mfma_f32_16x16x32_bf16(a1, qB[1], acc0, 0, 0, 0);
      acc1 = __builtin_amdgcn_mfma_f32_16x16x32_bf16(a2, qB[0], acc1, 0, 0, 0);
      acc1 = __builtin_amdgcn_mfma_f32_16x16x32_bf16(a3, qB[1], acc1, 0, 0, 0);
    }

    // mask + exp (lane's q = c; k = kwin + nb*16 + 4g + r)
    const uint32_t mw = mrowp[win];
    float e0[4], e1[4];
#pragma unroll
    for (int r = 0; r < 4; ++r) {
      e0[r] = ((mw >> (4 * g + r)) & 1u)      ? 1.0f : __expf(acc0[r] * scale);
      e1[r] = ((mw >> (16 + 4 * g + r)) & 1u) ? 1.0f : __expf(acc1[r] * scale);
      rsv += e0[r] + e1[r];
    }
    uint32_t es0 = cvtpk(e0[0], e0[1]), es1 = cvtpk(e0[2], e0[3]);
    uint32_t es2 = cvtpk(e1[0], e1[1]), es3 = cvtpk(e1[2], e1[3]);

    // E -> pair-shared LDS tile (one writer per pair; consumed after barrier)
    if (dhalf == 0) {
      uint2v lo, hi2;
      lo.x = es0; lo.y = es1; hi2.x = es2; hi2.y = es3;
      *(uint2v*)&etile[c * ETS + win * 32 + 4 * g]      = lo;
      *(uint2v*)&etile[c * ETS + win * 32 + 16 + 4 * g] = hi2;
    }

    // shuffle-transpose (R5): lane(g,c) = E[q=c][k = kwin + g*8 + 0..7]
    uint32_t x0 = __shfl(es0, srcA), y0 = __shfl(es2, srcA);
    uint32_t x1 = __shfl(es1, srcA), y1 = __shfl(es3, srcA);
    uint32_t x2 = __shfl(es0, srcB), y2 = __shfl(es2, srcB);
    uint32_t x3 = __shfl(es1, srcB), y3 = __shfl(es3, srcB);
    uint4v bb;
    bb.x = hi ? y0 : x0;
    bb.y = hi ? y1 : x1;
    bb.z = hi ? y2 : x2;
    bb.w = hi ? y3 : x3;
    const short8 bfrag = __builtin_bit_cast(short8, bb);

    // half-PV: this wave's 32 d-columns only
    short8 vA0, vA1;
    if (PREP) {
      const short* vb = VTp + (size_t)(dhalf * 32 + c) * S_ + kwin + g * 8;
      vA0 = *(const short8*)vb;
      vA1 = *(const short8*)(vb + 16 * (size_t)S_);
    } else {
      const float* vc = Vfp + (size_t)(kwin + g * 8) * D_ + dhalf * 32 + c;
#pragma unroll
      for (int e = 0; e < 8; ++e) {
        vA0[e] = f2bf(vc[(size_t)e * D_]);
        vA1[e] = f2bf(vc[(size_t)e * D_ + 16]);
      }
    }
    cacc[0] = __builtin_amdgcn_mfma_f32_16x16x32_bf16(vA0, bfrag, cacc[0], 0, 0, 0);
    cacc[1] = __builtin_amdgcn_mfma_f32_16x16x32_bf16(vA1, bfrag, cacc[1], 0, 0, 0);
  }

  // ---- reductions ----
  rsv += __shfl_xor(rsv, 16);
  rsv += __shfl_xor(rsv, 32);
  if (dhalf == 0 && lane < 16) atomicAdd(&lsum[lane], rsv);
#pragma unroll
  for (int nd = 0; nd < 2; ++nd)
#pragma unroll
    for (int r = 0; r < 4; ++r)
      atomicAdd(&cbuf[c * 65 + dhalf * 32 + nd * 16 + 4 * g + r], cacc[nd][r]);
  __syncthreads();

  if (tid < QBLK) linv[tid] = 1.0f / lsum[tid];
  __syncthreads();

  // ---- context write ----
  if (tid < QBLK * D_ / 4) {
    const int row = tid >> 4, d0 = (tid & 15) * 4;
    const float inv = linv[row];
    float4v cv;
    cv.x = cbuf[row * 65 + d0 + 0] * inv;
    cv.y = cbuf[row * 65 + d0 + 1] * inv;
    cv.z = cbuf[row * 65 + d0 + 2] * inv;
    cv.w = cbuf[row * 65 + d0 + 3] * inv;
    *(float4v*)&outC[((size_t)(bh * S_ + q0 + row)) * D_ + d0] = cv;
  }

  // ---- phase 2: full-line normalized attention stores ----
  // 128 threads (one pair) stream their 16x256 tile: 2 rows/iter x 8 iters
  {
    const int tloc  = tid & 127;
    const int rhalf = tloc >> 6;                // 0..1
    const int col4  = (tloc & 63) * 4;          // 0..252
    const short* et = etileA + pair * 16 * ETS;
    float* abase = outA + ((size_t)(bh * S_ + q0)) * S_ + kslab0 + col4;
#pragma unroll
    for (int it = 0; it < 8; ++it) {
      const int row = it * 2 + rhalf;
      const float inv = linv[row];
      const uint2v ev = *(const uint2v*)&et[row * ETS + col4];
      float4v av;
      av.x = bf2f((short)(ev.x & 0xffff)) * inv;
      av.y = bf2f((short)(ev.x >> 16))    * inv;
      av.z = bf2f((short)(ev.y & 0xffff)) * inv;
      av.w = bf2f((short)(ev.y >> 16))    * inv;
      __builtin_nontemporal_store(av, (float4v*)(abase + (size_t)row * S_));
    }
  }
}

extern "C" void kernel_launch(void* const* d_in, const int* in_sizes, int n_in,
                              void* d_out, int out_size, void* d_ws, size_t ws_size,
                              hipStream_t stream) {
  const float*   Q     = (const float*)d_in[0];
  const float*   K     = (const float*)d_in[1];
  const float*   V     = (const float*)d_in[2];
  const float*   scale = (const float*)d_in[3];
  const uint8_t* M     = (const uint8_t*)d_in[4];
  uint32_t* flag = (uint32_t*)d_ws;
  short* Kbf = (short*)((char*)d_ws + KBF_OFF);
  short* VT  = (short*)((char*)d_ws + VT_OFF);
  float* outC = (float*)d_out;
  float* outA = outC + (size_t)B_ * H_ * S_ * D_;

  hipMemsetAsync(flag, 0, 4, stream);
  detect_mask_dtype<<<dim3(1), dim3(256), 0, stream>>>(M, flag);

  const bool prep = ws_size >= VT_OFF + VT_BYTES;
  const int grid = B_ * H_ * (S_ / QBLK);       // 8192
  if (prep) {
    prep_k<<<dim3((B_ * H_ * S_ * D_) / (256 * 8)), dim3(256), 0, stream>>>(K, Kbf);
    prep_vt<<<dim3(B_ * H_ * (S_ / 64)), dim3(256), 0, stream>>>(V, VT);
    hipFuncSetAttribute(reinterpret_cast<const void*>(attn_fused<1>),
                        hipFuncAttributeMaxDynamicSharedMemorySize, SMEM_BYTES);
    attn_fused<1><<<dim3(grid), dim3(NTH), SMEM_BYTES, stream>>>(
        Q, K, V, scale, M, flag, Kbf, VT, outC, outA);
  } else {
    hipFuncSetAttribute(reinterpret_cast<const void*>(attn_fused<0>),
                        hipFuncAttributeMaxDynamicSharedMemorySize, SMEM_BYTES);
    attn_fused<0><<<dim3(grid), dim3(NTH), SMEM_BYTES, stream>>>(
        Q, K, V, scale, M, flag, Kbf, VT, outC, outA);
  }
}

// Round 13
// 1246.046 us; speedup vs baseline: 1.4174x; 1.1169x over previous
//
#include <hip/hip_runtime.h>
#include <stdint.h>

#define B_ 4
#define H_ 16
#define S_ 2048
#define D_ 64
#define NTH 512
#define NWAVES 8
#define QB 128                        /* q-rows per block (16 per wave) */
#define NWIN 64                       /* 32-k windows, full S */
#define EBS 40                        /* ebounce row stride (shorts) */

typedef __attribute__((ext_vector_type(8))) short short8;
typedef __attribute__((ext_vector_type(4))) float float4v;
typedef __attribute__((ext_vector_type(4))) unsigned int uint4v;
typedef __attribute__((ext_vector_type(2))) unsigned int uint2v;

static __device__ __forceinline__ short f2bf(float f) {
  uint32_t u = __builtin_bit_cast(uint32_t, f);
  u = (u + 0x7FFFu + ((u >> 16) & 1u)) >> 16;   // RNE
  return (short)u;
}
static __device__ __forceinline__ uint32_t cvtpk(float lo, float hi) {
  uint32_t r;
  asm("v_cvt_pk_bf16_f32 %0, %1, %2" : "=v"(r) : "v"(lo), "v"(hi));
  return r;
}
static __device__ __forceinline__ uint32_t nz4(uint32_t d) {
  uint32_t x = (d & 0x7F7F7F7Fu) + 0x7F7F7F7Fu;
  x = (x | d) & 0x80808080u;
  return x >> 7;
}
static __device__ __forceinline__ uint32_t nib(uint32_t d) {
  return ((nz4(d) * 0x01020408u) >> 24) & 0xFu;
}

#define KBF_OFF    ((size_t)64)
#define KBF_BYTES  ((size_t)B_ * H_ * S_ * D_ * 2)
#define VT_OFF     (KBF_OFF + KBF_BYTES)
#define VT_BYTES   ((size_t)B_ * H_ * S_ * D_ * 2)

__global__ void detect_mask_dtype(const uint8_t* __restrict__ m, uint32_t* flag) {
  uint32_t a = 0, b = 0;
  for (int i = threadIdx.x; i < 65536; i += 256) {
    uint8_t x = m[i];
    if (i & 3) a |= x; else b |= x;
  }
  uint32_t bits = (a ? 1u : 0u) | (b ? 2u : 0u);
  if (bits) atomicOr(flag, bits);
}

__global__ __launch_bounds__(256) void prep_k(const float* __restrict__ K,
                                              short* __restrict__ Kbf) {
  size_t base = ((size_t)blockIdx.x * 256 + threadIdx.x) * 8;
  float4v a = __builtin_nontemporal_load((const float4v*)(K + base));
  float4v b = __builtin_nontemporal_load((const float4v*)(K + base + 4));
  short8 o;
  o[0]=f2bf(a.x); o[1]=f2bf(a.y); o[2]=f2bf(a.z); o[3]=f2bf(a.w);
  o[4]=f2bf(b.x); o[5]=f2bf(b.y); o[6]=f2bf(b.z); o[7]=f2bf(b.w);
  *(short8*)(Kbf + base) = o;
}

__global__ __launch_bounds__(256) void prep_vt(const float* __restrict__ V,
                                               short* __restrict__ VT) {
  __shared__ short tile[64][72];
  int bh = blockIdx.x >> 5, k0 = (blockIdx.x & 31) * 64;
  const float* src = V + ((size_t)bh * S_ + k0) * D_;
  int t = threadIdx.x;
  int r = t >> 2, c0 = (t & 3) * 16;
#pragma unroll
  for (int j = 0; j < 4; ++j) {
    float4v f = __builtin_nontemporal_load((const float4v*)(src + (size_t)r * D_ + c0 + j * 4));
    tile[r][c0 + j*4 + 0] = f2bf(f.x);
    tile[r][c0 + j*4 + 1] = f2bf(f.y);
    tile[r][c0 + j*4 + 2] = f2bf(f.z);
    tile[r][c0 + j*4 + 3] = f2bf(f.w);
  }
  __syncthreads();
  int d = t >> 2, ks0 = (t & 3) * 16;
  short* dst = VT + (size_t)bh * D_ * S_ + (size_t)d * S_ + k0 + ks0;
#pragma unroll
  for (int half = 0; half < 2; ++half) {
    short8 o;
#pragma unroll
    for (int i = 0; i < 8; ++i) o[i] = tile[ks0 + half * 8 + i][d];
    *(short8*)(dst + half * 8) = o;
  }
}

template <int PREP>
__global__ __launch_bounds__(NTH, 6) void attn_fused(
    const float* __restrict__ Q, const float* __restrict__ K,
    const float* __restrict__ V, const float* __restrict__ scale_p,
    const uint8_t* __restrict__ M, const uint32_t* __restrict__ flag,
    const short* __restrict__ Kbf, const short* __restrict__ VT,
    float* __restrict__ outC, float* __restrict__ outA)
{
  __shared__ uint32_t mbits[128 * 68];          // mask stride 65; ctx-alias stride 68
  __shared__ short kbuf[2][32 * 64];            // K window dbuf (XOR-swizzled)
  __shared__ short ebounce[NWAVES][16 * EBS];   // per-wave PV transpose

  // bh-chunked XCD swizzle: 1024 blocks, XCD x gets bh [x*8, x*8+8)
  const int bx  = (blockIdx.x & 7) * 128 + (blockIdx.x >> 3);
  const int bh  = bx >> 4;
  const int q0  = (bx & 15) * QB;

  const int tid  = threadIdx.x;
  const int widx = tid >> 6;
  const int lane = tid & 63;
  const int g    = lane >> 4;
  const int c    = lane & 15;
  const int qrow = q0 + widx * 16 + c;          // this lane's q-row

  const float scale = scale_p[0];
  const uint32_t fl = flag[0];

  const short* Kbp = Kbf + (size_t)bh * S_ * D_;
  const short* VTp = VT + (size_t)bh * D_ * S_;
  const float* Kfp = K + (size_t)bh * S_ * D_;
  const float* Vfp = V + (size_t)bh * S_ * D_;

  // ---- mask bitmap prologue: [128][2048] bits (stride 65) ----
  {
    const int row = tid >> 2;
    const int wq0 = (tid & 3) * 16;
    if (fl == 3u) {
      const uint8_t* mrow = M + ((size_t)(bh * S_ + q0 + row)) * S_ + wq0 * 32;
#pragma unroll
      for (int j = 0; j < 16; ++j) {
        uint4v a = __builtin_nontemporal_load((const uint4v*)(mrow + j * 32));
        uint4v b = __builtin_nontemporal_load((const uint4v*)(mrow + j * 32 + 16));
        mbits[row * 65 + wq0 + j] =
            nib(a.x) | (nib(a.y) << 4) | (nib(a.z) << 8)  | (nib(a.w) << 12)
          | (nib(b.x) << 16) | (nib(b.y) << 20) | (nib(b.z) << 24) | (nib(b.w) << 28);
      }
    } else {
      const uint32_t* mrow = (const uint32_t*)M + ((size_t)(bh * S_ + q0 + row)) * S_ + wq0 * 32;
#pragma unroll
      for (int j = 0; j < 16; ++j) {
        uint32_t bits = 0;
#pragma unroll
        for (int u = 0; u < 8; ++u) {
          uint4v wv = __builtin_nontemporal_load((const uint4v*)(mrow + j * 32 + u * 4));
          uint32_t nzb = (wv.x ? 1u : 0u) | (wv.y ? 2u : 0u) | (wv.z ? 4u : 0u) | (wv.w ? 8u : 0u);
          bits |= nzb << (u * 4);
        }
        mbits[row * 65 + wq0 + j] = bits;
      }
    }
  }

  // ---- Q as B-frag: lane holds Q[qrow][.] ----
  short8 qB[2];
  {
    const float* qr = Q + ((size_t)(bh * S_ + qrow)) * D_;
    float4v x0 = *(const float4v*)(qr + g * 8);
    float4v x1 = *(const float4v*)(qr + g * 8 + 4);
    float4v y0 = *(const float4v*)(qr + 32 + g * 8);
    float4v y1 = *(const float4v*)(qr + 32 + g * 8 + 4);
    short8 f;
    f[0]=f2bf(x0.x); f[1]=f2bf(x0.y); f[2]=f2bf(x0.z); f[3]=f2bf(x0.w);
    f[4]=f2bf(x1.x); f[5]=f2bf(x1.y); f[6]=f2bf(x1.z); f[7]=f2bf(x1.w);
    qB[0] = f;
    f[0]=f2bf(y0.x); f[1]=f2bf(y0.y); f[2]=f2bf(y0.z); f[3]=f2bf(y0.w);
    f[4]=f2bf(y1.x); f[5]=f2bf(y1.y); f[6]=f2bf(y1.z); f[7]=f2bf(y1.w);
    qB[1] = f;
  }

  // ---- K staging (4 low waves, 16B/lane; XOR-swizzled LDS dest) ----
  const bool stager = (widx < 4);
  const int  sr = (widx << 3) + (lane >> 3);    // tile row 0..31
  const int  sp = lane & 7;                     // chunk 0..7
  const int  sdst = sr * 64 + ((sp ^ (sr & 7)) << 3);   // shorts
  short8  kreg;
  float4v kf0, kf1;
#define ISSUEK(W) do { if (stager) {                                           \
    if (PREP) kreg = *(const short8*)(Kbp + (size_t)((W) * 32 + sr) * 64 + sp * 8); \
    else { const float* s_ = Kfp + (size_t)((W) * 32 + sr) * 64 + sp * 8;      \
           kf0 = *(const float4v*)s_; kf1 = *(const float4v*)(s_ + 4); } } } while (0)
#define WRITEK(BUF) do { if (stager) {                                         \
    short8 o_;                                                                 \
    if (PREP) o_ = kreg;                                                       \
    else { o_[0]=f2bf(kf0.x); o_[1]=f2bf(kf0.y); o_[2]=f2bf(kf0.z); o_[3]=f2bf(kf0.w); \
           o_[4]=f2bf(kf1.x); o_[5]=f2bf(kf1.y); o_[6]=f2bf(kf1.z); o_[7]=f2bf(kf1.w); } \
    *(short8*)&kbuf[BUF][sdst] = o_; } } while (0)

  const int ka0 = ((g       ^ (c & 7)) << 3);   // frag chunk offsets (shorts)
  const int ka1 = (((g + 4) ^ (c & 7)) << 3);
  const uint32_t* mrow = &mbits[(widx * 16 + c) * 65];

  // ================= sweep 1: rowsum + unnormalized PV =================
  ISSUEK(0); WRITEK(0); ISSUEK(1);
  __syncthreads();

  float rsv = 0.0f;
  float4v cacc[4];
#pragma unroll
  for (int nd = 0; nd < 4; ++nd) cacc[nd] = (float4v){0.f, 0.f, 0.f, 0.f};
  short* eb = &ebounce[widx][0];

#pragma unroll 1
  for (int w = 0; w < NWIN; ++w) {
    const int cur = w & 1;
    const int kwin = w * 32;

    // V frags early (consumed at PV, ~full window of hiding)
    short8 vA0, vA1, vA2, vA3;
    if (PREP) {
      const short* vb = VTp + (size_t)c * S_ + kwin + g * 8;
      vA0 = *(const short8*)vb;
      vA1 = *(const short8*)(vb + 16 * (size_t)S_);
      vA2 = *(const short8*)(vb + 32 * (size_t)S_);
      vA3 = *(const short8*)(vb + 48 * (size_t)S_);
    } else {
      const float* vc = Vfp + (size_t)(kwin + g * 8) * D_ + c;
#pragma unroll
      for (int e = 0; e < 8; ++e) {
        vA0[e] = f2bf(vc[(size_t)e * D_]);
        vA1[e] = f2bf(vc[(size_t)e * D_ + 16]);
        vA2[e] = f2bf(vc[(size_t)e * D_ + 32]);
        vA3[e] = f2bf(vc[(size_t)e * D_ + 48]);
      }
    }

    const short* kb = &kbuf[cur][0];
    short8 a0 = *(const short8*)(kb + c * 64 + ka0);
    short8 a1 = *(const short8*)(kb + c * 64 + ka1);
    short8 a2 = *(const short8*)(kb + (c + 16) * 64 + ka0);
    short8 a3 = *(const short8*)(kb + (c + 16) * 64 + ka1);

    float4v acc0 = (float4v){0.f,0.f,0.f,0.f};
    float4v acc1 = (float4v){0.f,0.f,0.f,0.f};
    acc0 = __builtin_amdgcn_mfma_f32_16x16x32_bf16(a0, qB[0], acc0, 0, 0, 0);
    acc0 = __builtin_amdgcn_mfma_f32_16x16x32_bf16(a1, qB[1], acc0, 0, 0, 0);
    acc1 = __builtin_amdgcn_mfma_f32_16x16x32_bf16(a2, qB[0], acc1, 0, 0, 0);
    acc1 = __builtin_amdgcn_mfma_f32_16x16x32_bf16(a3, qB[1], acc1, 0, 0, 0);

    const uint32_t mw = mrow[w];
    float e0[4], e1[4];
#pragma unroll
    for (int r = 0; r < 4; ++r) {
      e0[r] = ((mw >> (4 * g + r)) & 1u)      ? 1.0f : __expf(acc0[r] * scale);
      e1[r] = ((mw >> (16 + 4 * g + r)) & 1u) ? 1.0f : __expf(acc1[r] * scale);
      rsv += e0[r] + e1[r];
    }
    // per-wave LDS bounce -> PV B-frag (k-consecutive layout)
    uint2v lo, hi2;
    lo.x  = cvtpk(e0[0], e0[1]);  lo.y  = cvtpk(e0[2], e0[3]);
    hi2.x = cvtpk(e1[0], e1[1]);  hi2.y = cvtpk(e1[2], e1[3]);
    *(uint2v*)&eb[c * EBS + 4 * g]      = lo;
    *(uint2v*)&eb[c * EBS + 16 + 4 * g] = hi2;
    const short8 bfrag = *(const short8*)&eb[c * EBS + g * 8];

    cacc[0] = __builtin_amdgcn_mfma_f32_16x16x32_bf16(vA0, bfrag, cacc[0], 0, 0, 0);
    cacc[1] = __builtin_amdgcn_mfma_f32_16x16x32_bf16(vA1, bfrag, cacc[1], 0, 0, 0);
    cacc[2] = __builtin_amdgcn_mfma_f32_16x16x32_bf16(vA2, bfrag, cacc[2], 0, 0, 0);
    cacc[3] = __builtin_amdgcn_mfma_f32_16x16x32_bf16(vA3, bfrag, cacc[3], 0, 0, 0);

    if (w + 1 < NWIN) {
      WRITEK(cur ^ 1);
      if (w + 2 < NWIN) ISSUEK(w + 2);
      __syncthreads();
    }
  }
  rsv += __shfl_xor(rsv, 16);
  rsv += __shfl_xor(rsv, 32);
  const float linv = 1.0f / rsv;                // lane's q-row inverse sum
  __syncthreads();

  // ================= sweep 2: recompute + normalized attention stores =====
  ISSUEK(0); WRITEK(0); ISSUEK(1);
  __syncthreads();

  float* arow = outA + ((size_t)(bh * S_ + qrow)) * S_;
#pragma unroll 1
  for (int w = 0; w < NWIN; ++w) {
    const int cur = w & 1;
    const int kwin = w * 32;

    const short* kb = &kbuf[cur][0];
    short8 a0 = *(const short8*)(kb + c * 64 + ka0);
    short8 a1 = *(const short8*)(kb + c * 64 + ka1);
    short8 a2 = *(const short8*)(kb + (c + 16) * 64 + ka0);
    short8 a3 = *(const short8*)(kb + (c + 16) * 64 + ka1);

    float4v acc0 = (float4v){0.f,0.f,0.f,0.f};
    float4v acc1 = (float4v){0.f,0.f,0.f,0.f};
    acc0 = __builtin_amdgcn_mfma_f32_16x16x32_bf16(a0, qB[0], acc0, 0, 0, 0);
    acc0 = __builtin_amdgcn_mfma_f32_16x16x32_bf16(a1, qB[1], acc0, 0, 0, 0);
    acc1 = __builtin_amdgcn_mfma_f32_16x16x32_bf16(a2, qB[0], acc1, 0, 0, 0);
    acc1 = __builtin_amdgcn_mfma_f32_16x16x32_bf16(a3, qB[1], acc1, 0, 0, 0);

    const uint32_t mw = mrow[w];
    float4v n0, n1;
#pragma unroll
    for (int r = 0; r < 4; ++r) {
      n0[r] = (((mw >> (4 * g + r)) & 1u)      ? 1.0f : __expf(acc0[r] * scale)) * linv;
      n1[r] = (((mw >> (16 + 4 * g + r)) & 1u) ? 1.0f : __expf(acc1[r] * scale)) * linv;
    }
    __builtin_nontemporal_store(n0, (float4v*)(arow + kwin + 4 * g));
    __builtin_nontemporal_store(n1, (float4v*)(arow + kwin + 16 + 4 * g));

    if (w + 1 < NWIN) {
      WRITEK(cur ^ 1);
      if (w + 2 < NWIN) ISSUEK(w + 2);
      __syncthreads();
    }
  }
#undef ISSUEK
#undef WRITEK
  __syncthreads();                              // mask dead; alias mbits for ctx

  // ---- context epilogue: normalize cacc, LDS transpose, coalesced store ----
  {
    float* cst = (float*)mbits;                 // [128][68] floats
#pragma unroll
    for (int nd = 0; nd < 4; ++nd) {
      float4v v;
#pragma unroll
      for (int r = 0; r < 4; ++r) v[r] = cacc[nd][r] * linv;
      *(float4v*)&cst[(widx * 16 + c) * 68 + nd * 16 + 4 * g] = v;
    }
    __syncthreads();
    const int qq = tid >> 2, ch = tid & 3;
    const float* src = &cst[qq * 68 + ch * 16];
    float* dst = outC + ((size_t)(bh * S_ + q0 + qq)) * D_ + ch * 16;
    float4v c0 = *(const float4v*)src;
    float4v c1 = *(const float4v*)(src + 4);
    float4v c2 = *(const float4v*)(src + 8);
    float4v c3 = *(const float4v*)(src + 12);
    __builtin_nontemporal_store(c0, (float4v*)dst);
    __builtin_nontemporal_store(c1, (float4v*)(dst + 4));
    __builtin_nontemporal_store(c2, (float4v*)(dst + 8));
    __builtin_nontemporal_store(c3, (float4v*)(dst + 12));
  }
}

extern "C" void kernel_launch(void* const* d_in, const int* in_sizes, int n_in,
                              void* d_out, int out_size, void* d_ws, size_t ws_size,
                              hipStream_t stream) {
  const float*   Q     = (const float*)d_in[0];
  const float*   K     = (const float*)d_in[1];
  const float*   V     = (const float*)d_in[2];
  const float*   scale = (const float*)d_in[3];
  const uint8_t* M     = (const uint8_t*)d_in[4];
  uint32_t* flag = (uint32_t*)d_ws;
  short* Kbf = (short*)((char*)d_ws + KBF_OFF);
  short* VT  = (short*)((char*)d_ws + VT_OFF);
  float* outC = (float*)d_out;
  float* outA = outC + (size_t)B_ * H_ * S_ * D_;

  hipMemsetAsync(flag, 0, 4, stream);
  detect_mask_dtype<<<dim3(1), dim3(256), 0, stream>>>(M, flag);

  const bool prep = ws_size >= VT_OFF + VT_BYTES;
  const int grid = B_ * H_ * (S_ / QB);         // 1024
  if (prep) {
    prep_k<<<dim3((B_ * H_ * S_ * D_) / (256 * 8)), dim3(256), 0, stream>>>(K, Kbf);
    prep_vt<<<dim3(B_ * H_ * (S_ / 64)), dim3(256), 0, stream>>>(V, VT);
    attn_fused<1><<<dim3(grid), dim3(NTH), 0, stream>>>(
        Q, K, V, scale, M, flag, Kbf, VT, outC, outA);
  } else {
    attn_fused<0><<<dim3(grid), dim3(NTH), 0, stream>>>(
        Q, K, V, scale, M, flag, Kbf, VT, outC, outA);
  }
}

// Round 14
// 1130.186 us; speedup vs baseline: 1.5627x; 1.1025x over previous
//
#include <hip/hip_runtime.h>
#include <stdint.h>

#define B_ 4
#define H_ 16
#define S_ 2048
#define D_ 64
#define NTH 512
#define NWAVES 8
#define QB 128                        /* q-rows per block (16 per wave) */
#define NWIN 64                       /* 32-k windows, full S */
#define EBS 40                        /* ebounce row stride (shorts) */

typedef __attribute__((ext_vector_type(8))) short short8;
typedef __attribute__((ext_vector_type(4))) float float4v;
typedef __attribute__((ext_vector_type(4))) unsigned int uint4v;
typedef __attribute__((ext_vector_type(2))) unsigned int uint2v;

static __device__ __forceinline__ short f2bf(float f) {
  uint32_t u = __builtin_bit_cast(uint32_t, f);
  u = (u + 0x7FFFu + ((u >> 16) & 1u)) >> 16;   // RNE
  return (short)u;
}
static __device__ __forceinline__ float bf2f(uint32_t s) {
  return __builtin_bit_cast(float, s << 16);
}
static __device__ __forceinline__ uint32_t cvtpk(float lo, float hi) {
  uint32_t r;
  asm("v_cvt_pk_bf16_f32 %0, %1, %2" : "=v"(r) : "v"(lo), "v"(hi));
  return r;
}
static __device__ __forceinline__ uint32_t nz4(uint32_t d) {
  uint32_t x = (d & 0x7F7F7F7Fu) + 0x7F7F7F7Fu;
  x = (x | d) & 0x80808080u;
  return x >> 7;
}
static __device__ __forceinline__ uint32_t nib(uint32_t d) {
  return ((nz4(d) * 0x01020408u) >> 24) & 0xFu;
}

#define KBF_OFF    ((size_t)64)
#define KBF_BYTES  ((size_t)B_ * H_ * S_ * D_ * 2)
#define VT_OFF     (KBF_OFF + KBF_BYTES)
#define VT_BYTES   ((size_t)B_ * H_ * S_ * D_ * 2)

__global__ void detect_mask_dtype(const uint8_t* __restrict__ m, uint32_t* flag) {
  uint32_t a = 0, b = 0;
  for (int i = threadIdx.x; i < 65536; i += 256) {
    uint8_t x = m[i];
    if (i & 3) a |= x; else b |= x;
  }
  uint32_t bits = (a ? 1u : 0u) | (b ? 2u : 0u);
  if (bits) atomicOr(flag, bits);
}

__global__ __launch_bounds__(256) void prep_k(const float* __restrict__ K,
                                              short* __restrict__ Kbf) {
  size_t base = ((size_t)blockIdx.x * 256 + threadIdx.x) * 8;
  float4v a = __builtin_nontemporal_load((const float4v*)(K + base));
  float4v b = __builtin_nontemporal_load((const float4v*)(K + base + 4));
  short8 o;
  o[0]=f2bf(a.x); o[1]=f2bf(a.y); o[2]=f2bf(a.z); o[3]=f2bf(a.w);
  o[4]=f2bf(b.x); o[5]=f2bf(b.y); o[6]=f2bf(b.z); o[7]=f2bf(b.w);
  *(short8*)(Kbf + base) = o;
}

__global__ __launch_bounds__(256) void prep_vt(const float* __restrict__ V,
                                               short* __restrict__ VT) {
  __shared__ short tile[64][72];
  int bh = blockIdx.x >> 5, k0 = (blockIdx.x & 31) * 64;
  const float* src = V + ((size_t)bh * S_ + k0) * D_;
  int t = threadIdx.x;
  int r = t >> 2, c0 = (t & 3) * 16;
#pragma unroll
  for (int j = 0; j < 4; ++j) {
    float4v f = __builtin_nontemporal_load((const float4v*)(src + (size_t)r * D_ + c0 + j * 4));
    tile[r][c0 + j*4 + 0] = f2bf(f.x);
    tile[r][c0 + j*4 + 1] = f2bf(f.y);
    tile[r][c0 + j*4 + 2] = f2bf(f.z);
    tile[r][c0 + j*4 + 3] = f2bf(f.w);
  }
  __syncthreads();
  int d = t >> 2, ks0 = (t & 3) * 16;
  short* dst = VT + (size_t)bh * D_ * S_ + (size_t)d * S_ + k0 + ks0;
#pragma unroll
  for (int half = 0; half < 2; ++half) {
    short8 o;
#pragma unroll
    for (int i = 0; i < 8; ++i) o[i] = tile[ks0 + half * 8 + i][d];
    *(short8*)(dst + half * 8) = o;
  }
}

template <int PREP>
__global__ __launch_bounds__(NTH, 6) void attn_fused(
    const float* __restrict__ Q, const float* __restrict__ K,
    const float* __restrict__ V, const float* __restrict__ scale_p,
    const uint8_t* __restrict__ M, const uint32_t* __restrict__ flag,
    const short* __restrict__ Kbf, const short* __restrict__ VT,
    float* __restrict__ outC, float* __restrict__ outA)
{
  __shared__ uint32_t mbits[128 * 68];          // mask stride 65; ctx-alias stride 68
  __shared__ short kbuf[2][32 * 64];            // K window dbuf (XOR-swizzled)
  __shared__ short ebounce[NWAVES][16 * EBS];   // per-wave E bounce
  __shared__ float linvW[NWAVES][16];           // per-wave row inverse sums

  // bh-chunked XCD swizzle: 1024 blocks, XCD x gets bh [x*8, x*8+8)
  const int bx  = (blockIdx.x & 7) * 128 + (blockIdx.x >> 3);
  const int bh  = bx >> 4;
  const int q0  = (bx & 15) * QB;

  const int tid  = threadIdx.x;
  const int widx = tid >> 6;
  const int lane = tid & 63;
  const int g    = lane >> 4;
  const int c    = lane & 15;
  const int qrow = q0 + widx * 16 + c;          // this lane's q-row

  const float scale = scale_p[0];
  const uint32_t fl = flag[0];

  const short* Kbp = Kbf + (size_t)bh * S_ * D_;
  const short* VTp = VT + (size_t)bh * D_ * S_;
  const float* Kfp = K + (size_t)bh * S_ * D_;
  const float* Vfp = V + (size_t)bh * S_ * D_;

  // ---- mask bitmap prologue: [128][2048] bits (stride 65) ----
  {
    const int row = tid >> 2;
    const int wq0 = (tid & 3) * 16;
    if (fl == 3u) {
      const uint8_t* mrow = M + ((size_t)(bh * S_ + q0 + row)) * S_ + wq0 * 32;
#pragma unroll
      for (int j = 0; j < 16; ++j) {
        uint4v a = __builtin_nontemporal_load((const uint4v*)(mrow + j * 32));
        uint4v b = __builtin_nontemporal_load((const uint4v*)(mrow + j * 32 + 16));
        mbits[row * 65 + wq0 + j] =
            nib(a.x) | (nib(a.y) << 4) | (nib(a.z) << 8)  | (nib(a.w) << 12)
          | (nib(b.x) << 16) | (nib(b.y) << 20) | (nib(b.z) << 24) | (nib(b.w) << 28);
      }
    } else {
      const uint32_t* mrow = (const uint32_t*)M + ((size_t)(bh * S_ + q0 + row)) * S_ + wq0 * 32;
#pragma unroll
      for (int j = 0; j < 16; ++j) {
        uint32_t bits = 0;
#pragma unroll
        for (int u = 0; u < 8; ++u) {
          uint4v wv = __builtin_nontemporal_load((const uint4v*)(mrow + j * 32 + u * 4));
          uint32_t nzb = (wv.x ? 1u : 0u) | (wv.y ? 2u : 0u) | (wv.z ? 4u : 0u) | (wv.w ? 8u : 0u);
          bits |= nzb << (u * 4);
        }
        mbits[row * 65 + wq0 + j] = bits;
      }
    }
  }

  // ---- Q as B-frag: lane holds Q[qrow][.] ----
  short8 qB[2];
  {
    const float* qr = Q + ((size_t)(bh * S_ + qrow)) * D_;
    float4v x0 = *(const float4v*)(qr + g * 8);
    float4v x1 = *(const float4v*)(qr + g * 8 + 4);
    float4v y0 = *(const float4v*)(qr + 32 + g * 8);
    float4v y1 = *(const float4v*)(qr + 32 + g * 8 + 4);
    short8 f;
    f[0]=f2bf(x0.x); f[1]=f2bf(x0.y); f[2]=f2bf(x0.z); f[3]=f2bf(x0.w);
    f[4]=f2bf(x1.x); f[5]=f2bf(x1.y); f[6]=f2bf(x1.z); f[7]=f2bf(x1.w);
    qB[0] = f;
    f[0]=f2bf(y0.x); f[1]=f2bf(y0.y); f[2]=f2bf(y0.z); f[3]=f2bf(y0.w);
    f[4]=f2bf(y1.x); f[5]=f2bf(y1.y); f[6]=f2bf(y1.z); f[7]=f2bf(y1.w);
    qB[1] = f;
  }

  // ---- K staging (4 low waves, 16B/lane; XOR-swizzled LDS dest) ----
  const bool stager = (widx < 4);
  const int  sr = (widx << 3) + (lane >> 3);    // tile row 0..31
  const int  sp = lane & 7;                     // chunk 0..7
  const int  sdst = sr * 64 + ((sp ^ (sr & 7)) << 3);   // shorts
  short8  kreg;
  float4v kf0, kf1;
#define ISSUEK(W) do { if (stager) {                                           \
    if (PREP) kreg = *(const short8*)(Kbp + (size_t)((W) * 32 + sr) * 64 + sp * 8); \
    else { const float* s_ = Kfp + (size_t)((W) * 32 + sr) * 64 + sp * 8;      \
           kf0 = *(const float4v*)s_; kf1 = *(const float4v*)(s_ + 4); } } } while (0)
#define WRITEK(BUF) do { if (stager) {                                         \
    short8 o_;                                                                 \
    if (PREP) o_ = kreg;                                                       \
    else { o_[0]=f2bf(kf0.x); o_[1]=f2bf(kf0.y); o_[2]=f2bf(kf0.z); o_[3]=f2bf(kf0.w); \
           o_[4]=f2bf(kf1.x); o_[5]=f2bf(kf1.y); o_[6]=f2bf(kf1.z); o_[7]=f2bf(kf1.w); } \
    *(short8*)&kbuf[BUF][sdst] = o_; } } while (0)

  const int ka0 = ((g       ^ (c & 7)) << 3);   // frag chunk offsets (shorts)
  const int ka1 = (((g + 4) ^ (c & 7)) << 3);
  const uint32_t* mrow = &mbits[(widx * 16 + c) * 65];

  // ================= sweep 1: rowsum + unnormalized PV =================
  ISSUEK(0); WRITEK(0); ISSUEK(1);
  __syncthreads();

  float rsv = 0.0f;
  float4v cacc[4];
#pragma unroll
  for (int nd = 0; nd < 4; ++nd) cacc[nd] = (float4v){0.f, 0.f, 0.f, 0.f};
  short* eb = &ebounce[widx][0];

#pragma unroll 1
  for (int w = 0; w < NWIN; ++w) {
    const int cur = w & 1;
    const int kwin = w * 32;

    // V frags early (consumed at PV, ~full window of hiding)
    short8 vA0, vA1, vA2, vA3;
    if (PREP) {
      const short* vb = VTp + (size_t)c * S_ + kwin + g * 8;
      vA0 = *(const short8*)vb;
      vA1 = *(const short8*)(vb + 16 * (size_t)S_);
      vA2 = *(const short8*)(vb + 32 * (size_t)S_);
      vA3 = *(const short8*)(vb + 48 * (size_t)S_);
    } else {
      const float* vc = Vfp + (size_t)(kwin + g * 8) * D_ + c;
#pragma unroll
      for (int e = 0; e < 8; ++e) {
        vA0[e] = f2bf((uint32_t)(uint16_t)f2bf(vc[(size_t)e * D_])), vA0[e] = f2bf(vc[(size_t)e * D_]);
        vA1[e] = f2bf(vc[(size_t)e * D_ + 16]);
        vA2[e] = f2bf(vc[(size_t)e * D_ + 32]);
        vA3[e] = f2bf(vc[(size_t)e * D_ + 48]);
      }
    }

    const short* kb = &kbuf[cur][0];
    short8 a0 = *(const short8*)(kb + c * 64 + ka0);
    short8 a1 = *(const short8*)(kb + c * 64 + ka1);
    short8 a2 = *(const short8*)(kb + (c + 16) * 64 + ka0);
    short8 a3 = *(const short8*)(kb + (c + 16) * 64 + ka1);

    float4v acc0 = (float4v){0.f,0.f,0.f,0.f};
    float4v acc1 = (float4v){0.f,0.f,0.f,0.f};
    acc0 = __builtin_amdgcn_mfma_f32_16x16x32_bf16(a0, qB[0], acc0, 0, 0, 0);
    acc0 = __builtin_amdgcn_mfma_f32_16x16x32_bf16(a1, qB[1], acc0, 0, 0, 0);
    acc1 = __builtin_amdgcn_mfma_f32_16x16x32_bf16(a2, qB[0], acc1, 0, 0, 0);
    acc1 = __builtin_amdgcn_mfma_f32_16x16x32_bf16(a3, qB[1], acc1, 0, 0, 0);

    const uint32_t mw = mrow[w];
    float e0[4], e1[4];
#pragma unroll
    for (int r = 0; r < 4; ++r) {
      e0[r] = ((mw >> (4 * g + r)) & 1u)      ? 1.0f : __expf(acc0[r] * scale);
      e1[r] = ((mw >> (16 + 4 * g + r)) & 1u) ? 1.0f : __expf(acc1[r] * scale);
      rsv += e0[r] + e1[r];
    }
    // per-wave LDS bounce -> PV B-frag (k-consecutive layout)
    uint2v lo, hi2;
    lo.x  = cvtpk(e0[0], e0[1]);  lo.y  = cvtpk(e0[2], e0[3]);
    hi2.x = cvtpk(e1[0], e1[1]);  hi2.y = cvtpk(e1[2], e1[3]);
    *(uint2v*)&eb[c * EBS + 4 * g]      = lo;
    *(uint2v*)&eb[c * EBS + 16 + 4 * g] = hi2;
    const short8 bfrag = *(const short8*)&eb[c * EBS + g * 8];

    cacc[0] = __builtin_amdgcn_mfma_f32_16x16x32_bf16(vA0, bfrag, cacc[0], 0, 0, 0);
    cacc[1] = __builtin_amdgcn_mfma_f32_16x16x32_bf16(vA1, bfrag, cacc[1], 0, 0, 0);
    cacc[2] = __builtin_amdgcn_mfma_f32_16x16x32_bf16(vA2, bfrag, cacc[2], 0, 0, 0);
    cacc[3] = __builtin_amdgcn_mfma_f32_16x16x32_bf16(vA3, bfrag, cacc[3], 0, 0, 0);

    if (w + 1 < NWIN) {
      WRITEK(cur ^ 1);
      if (w + 2 < NWIN) ISSUEK(w + 2);
      __syncthreads();
    }
  }
  rsv += __shfl_xor(rsv, 16);
  rsv += __shfl_xor(rsv, 32);
  const float linv = 1.0f / rsv;                // lane's q-row inverse sum
  if (g == 0) linvW[widx][c] = linv;
  __syncthreads();

  // ================= sweep 2: recompute + full-line normalized stores =====
  ISSUEK(0); WRITEK(0); ISSUEK(1);
  __syncthreads();

  const int srow = lane >> 3;                   // store row 0..7 (+8)
  const int scol = (lane & 7) * 4;              // k offset within window
  float* arow0 = outA + ((size_t)(bh * S_ + q0 + widx * 16 + srow)) * S_ + scol;
  float* arow1 = outA + ((size_t)(bh * S_ + q0 + widx * 16 + srow + 8)) * S_ + scol;
  const float linr0 = linvW[widx][srow];
  const float linr1 = linvW[widx][srow + 8];

#pragma unroll 1
  for (int w = 0; w < NWIN; ++w) {
    const int cur = w & 1;
    const int kwin = w * 32;

    const short* kb = &kbuf[cur][0];
    short8 a0 = *(const short8*)(kb + c * 64 + ka0);
    short8 a1 = *(const short8*)(kb + c * 64 + ka1);
    short8 a2 = *(const short8*)(kb + (c + 16) * 64 + ka0);
    short8 a3 = *(const short8*)(kb + (c + 16) * 64 + ka1);

    float4v acc0 = (float4v){0.f,0.f,0.f,0.f};
    float4v acc1 = (float4v){0.f,0.f,0.f,0.f};
    acc0 = __builtin_amdgcn_mfma_f32_16x16x32_bf16(a0, qB[0], acc0, 0, 0, 0);
    acc0 = __builtin_amdgcn_mfma_f32_16x16x32_bf16(a1, qB[1], acc0, 0, 0, 0);
    acc1 = __builtin_amdgcn_mfma_f32_16x16x32_bf16(a2, qB[0], acc1, 0, 0, 0);
    acc1 = __builtin_amdgcn_mfma_f32_16x16x32_bf16(a3, qB[1], acc1, 0, 0, 0);

    const uint32_t mw = mrow[w];
    float e0[4], e1[4];
#pragma unroll
    for (int r = 0; r < 4; ++r) {
      e0[r] = ((mw >> (4 * g + r)) & 1u)      ? 1.0f : __expf(acc0[r] * scale);
      e1[r] = ((mw >> (16 + 4 * g + r)) & 1u) ? 1.0f : __expf(acc1[r] * scale);
    }
    uint2v lo, hi2;
    lo.x  = cvtpk(e0[0], e0[1]);  lo.y  = cvtpk(e0[2], e0[3]);
    hi2.x = cvtpk(e1[0], e1[1]);  hi2.y = cvtpk(e1[2], e1[3]);
    *(uint2v*)&eb[c * EBS + 4 * g]      = lo;
    *(uint2v*)&eb[c * EBS + 16 + 4 * g] = hi2;

    // full-128B-line stores: 8 rows per instruction (wave-private tile read)
    const uint2v ev0 = *(const uint2v*)&eb[srow * EBS + scol];
    const uint2v ev1 = *(const uint2v*)&eb[(srow + 8) * EBS + scol];
    float4v s0, s1;
    s0.x = bf2f(ev0.x & 0xffff) * linr0; s0.y = bf2f(ev0.x >> 16) * linr0;
    s0.z = bf2f(ev0.y & 0xffff) * linr0; s0.w = bf2f(ev0.y >> 16) * linr0;
    s1.x = bf2f(ev1.x & 0xffff) * linr1; s1.y = bf2f(ev1.x >> 16) * linr1;
    s1.z = bf2f(ev1.y & 0xffff) * linr1; s1.w = bf2f(ev1.y >> 16) * linr1;
    __builtin_nontemporal_store(s0, (float4v*)(arow0 + kwin));
    __builtin_nontemporal_store(s1, (float4v*)(arow1 + kwin));

    if (w + 1 < NWIN) {
      WRITEK(cur ^ 1);
      if (w + 2 < NWIN) ISSUEK(w + 2);
      __syncthreads();
    }
  }
#undef ISSUEK
#undef WRITEK
  __syncthreads();                              // mask dead; alias mbits for ctx

  // ---- context epilogue: normalize cacc, LDS transpose, coalesced store ----
  {
    float* cst = (float*)mbits;                 // [128][68] floats
#pragma unroll
    for (int nd = 0; nd < 4; ++nd) {
      float4v v;
#pragma unroll
      for (int r = 0; r < 4; ++r) v[r] = cacc[nd][r] * linv;
      *(float4v*)&cst[(widx * 16 + c) * 68 + nd * 16 + 4 * g] = v;
    }
    __syncthreads();
    const int qq = tid >> 2, ch = tid & 3;
    const float* src = &cst[qq * 68 + ch * 16];
    float* dst = outC + ((size_t)(bh * S_ + q0 + qq)) * D_ + ch * 16;
    float4v c0 = *(const float4v*)src;
    float4v c1 = *(const float4v*)(src + 4);
    float4v c2 = *(const float4v*)(src + 8);
    float4v c3 = *(const float4v*)(src + 12);
    __builtin_nontemporal_store(c0, (float4v*)dst);
    __builtin_nontemporal_store(c1, (float4v*)(dst + 4));
    __builtin_nontemporal_store(c2, (float4v*)(dst + 8));
    __builtin_nontemporal_store(c3, (float4v*)(dst + 12));
  }
}

extern "C" void kernel_launch(void* const* d_in, const int* in_sizes, int n_in,
                              void* d_out, int out_size, void* d_ws, size_t ws_size,
                              hipStream_t stream) {
  const float*   Q     = (const float*)d_in[0];
  const float*   K     = (const float*)d_in[1];
  const float*   V     = (const float*)d_in[2];
  const float*   scale = (const float*)d_in[3];
  const uint8_t* M     = (const uint8_t*)d_in[4];
  uint32_t* flag = (uint32_t*)d_ws;
  short* Kbf = (short*)((char*)d_ws + KBF_OFF);
  short* VT  = (short*)((char*)d_ws + VT_OFF);
  float* outC = (float*)d_out;
  float* outA = outC + (size_t)B_ * H_ * S_ * D_;

  hipMemsetAsync(flag, 0, 4, stream);
  detect_mask_dtype<<<dim3(1), dim3(256), 0, stream>>>(M, flag);

  const bool prep = ws_size >= VT_OFF + VT_BYTES;
  const int grid = B_ * H_ * (S_ / QB);         // 1024
  if (prep) {
    prep_k<<<dim3((B_ * H_ * S_ * D_) / (256 * 8)), dim3(256), 0, stream>>>(K, Kbf);
    prep_vt<<<dim3(B_ * H_ * (S_ / 64)), dim3(256), 0, stream>>>(V, VT);
    attn_fused<1><<<dim3(grid), dim3(NTH), 0, stream>>>(
        Q, K, V, scale, M, flag, Kbf, VT, outC, outA);
  } else {
    attn_fused<0><<<dim3(grid), dim3(NTH), 0, stream>>>(
        Q, K, V, scale, M, flag, Kbf, VT, outC, outA);
  }
}